// Round 14
// baseline (131.151 us; speedup 1.0000x reference)
//
#include <hip/hip_runtime.h>
#include <cstddef>

#define NB 4
#define NC 256
#define ND 128
#define NH 128
#define NW 128
#define NHW (NH*NW)
#define NT 16384
#define NBKT 1024   // 4 batches x 16x16 tiles of 8x8 px
#define CAP 192     // per-bucket capacity (mean 64, P(>192) ~ e^-64: never)
#define FS 136      // feat row stride in ushorts
#define GGRID 3072  // NBKT * ceil(CAP/64) chunk slots
#define CSTRIDE 16  // counts padded to 1 counter / 64B line (atomic contention fix)

typedef short   short8  __attribute__((ext_vector_type(8)));
typedef unsigned short ushort8 __attribute__((ext_vector_type(8)));
typedef float   floatx4 __attribute__((ext_vector_type(4)));
typedef float   floatx2 __attribute__((ext_vector_type(2)));

__device__ __forceinline__ unsigned pk_bf16(float a, float b) {
    unsigned ua = __float_as_uint(a);
    unsigned ub = __float_as_uint(b);
    ua += 0x7fffu + ((ua >> 16) & 1u);
    ub += 0x7fffu + ((ub >> 16) & 1u);
    return (ua >> 16) | (ub & 0xffff0000u);
}

// ---- fp8 e4m3 (OCP) HW cvt ----
__device__ __forceinline__ unsigned fp8x4_from_f32(float v0, float v1, float v2, float v3) {
    int r = 0;
    r = __builtin_amdgcn_cvt_pk_fp8_f32(v0, v1, r, false);
    r = __builtin_amdgcn_cvt_pk_fp8_f32(v2, v3, r, true);
    return (unsigned)r;
}
template <bool HI>
__device__ __forceinline__ floatx2 fp8x2_to_f32(unsigned w) {
    return __builtin_amdgcn_cvt_pk_f32_fp8((int)w, HI);
}

__device__ __forceinline__ int bucket_of(float cx, float cy, int b) {
    int x0 = (int)floorf(cx * (float)(NW - 1));
    int y0 = (int)floorf(cy * (float)(NH - 1));
    x0 = min(max(x0, 0), NW - 1);
    y0 = min(max(y0, 0), NH - 1);
    return b * 256 + (y0 >> 3) * 16 + (x0 >> 3);
}

// Prep: zero counts + pack W1->bf16 + pack Wp->fp8 A-fragments ONCE (R13:
// killed 67MB of per-block Wp re-reads, -6us).
__global__ __launch_bounds__(512)
void prep_kernel(const float* __restrict__ Wp, const float* __restrict__ W1,
                 int* __restrict__ counts, unsigned short* __restrict__ W1bf,
                 unsigned char* __restrict__ Wpbf8)
{
    const int gid = blockIdx.x * 512 + threadIdx.x;   // [0, 32768)
    if (gid < NBKT*CSTRIDE) counts[gid] = 0;
    if (gid < 16384) {
        unsigned u = __float_as_uint(W1[gid]);
        u += 0x7fffu + ((u >> 16) & 1u);
        W1bf[gid] = (unsigned short)(u >> 16);
    }
    if (gid < 4096) {   // fragment idx = (dt*8 + ch)*64 + lane
        const int lane = gid & 63;
        const int ch   = (gid >> 6) & 7;
        const int dt   = gid >> 9;
        const int l15  = lane & 15;
        const int q    = lane >> 4;
        const float* src = Wp + (size_t)(dt*16 + l15)*NC + ch*32 + q*8;
        float4 g0 = *(const float4*)src;
        float4 g1 = *(const float4*)(src + 4);
        uint2 pk = make_uint2(fp8x4_from_f32(g0.x,g0.y,g0.z,g0.w),
                              fp8x4_from_f32(g1.x,g1.y,g1.z,g1.w));
        *(uint2*)&Wpbf8[(size_t)gid*8] = pk;
    }
}

// Fused: binning prelude, then vm projection (fp8 MFMA).
// R14: 3-buffer LDS rotation -> 1 barrier/K-step (was 2) + prefetch depth 2
// (4 outstanding loads/thread, steady-state vmcnt(2)). stage(k+2) is issued
// AFTER barrier k: all waves passed it only after compute(k-1), the last
// reader of buffer (k+2)%3, so the trailing "free" barrier is redundant.
// LDS 32K awp + 3x16K = 80KB exactly -> 2 blocks/CU.
__global__ __launch_bounds__(512, 4)
void proj_fused(const float* __restrict__ fmap, const float* __restrict__ coords,
                const unsigned char* __restrict__ Wpbf8,
                int* __restrict__ counts, int* __restrict__ order,
                unsigned char* __restrict__ vm)
{
    const int bi = blockIdx.x;
    const int t  = threadIdx.x;

    // ---- prelude: bin 128 coords (t<128) ----
    if (t < 128) {
        const int g = bi * 128 + t;              // [0, 65536)
        const float cx = coords[(size_t)g*2 + 0];
        const float cy = coords[(size_t)g*2 + 1];
        const int bkt = bucket_of(cx, cy, g >> 14);
        const int pos = atomicAdd(&counts[bkt*CSTRIDE], 1);
        if (pos < CAP) order[bkt*CAP + pos] = g;
    }

    __shared__ unsigned char awp8[8*8*64*8];   // 32 KB fp8 A-fragments
    __shared__ float ftile[3][32*128];         // 3 x 16 KB rotating fmap tiles

    const int lane = t & 63;
    const int w    = t >> 6;
    const int l15  = lane & 15;
    const int q    = lane >> 4;
    const int cq   = q * 8;

    {   // stage pre-packed A-fragments: 32 KB linear copy
        const uint4* src = (const uint4*)Wpbf8;
        uint4* dst = (uint4*)awp8;
        #pragma unroll
        for (int i = 0; i < 4; ++i) dst[t + i*512] = src[t + i*512];
    }

    const int b    = (bi & 7) >> 1;
    const int slot = ((bi >> 3) << 1) | (bi & 1);
    const int pl   = w*16 + l15;                 // local pixel 0..127

    // staging geometry: 32 threads per 512B channel row, 16 rows per call
    const int row_thr = t >> 5;                  // 0..15
    const int px_off  = (t & 31) * 4;            // 0..124
    const float* gstage = fmap + (size_t)b*NC*NHW + slot*128 + px_off;
    char* ftile_b = (char*)ftile;
    const unsigned wbase = (unsigned)((t >> 6) * 1024);  // wave-uniform dest base

    floatx4 acc[8];
    #pragma unroll
    for (int i = 0; i < 8; ++i) acc[i] = (floatx4)(0.f);

    __syncthreads();   // awp copy + prelude drained

#define STAGE(K, NB_)  do {                                                          \
        const float* g0_ = gstage + (size_t)((K)*32 + row_thr)*NHW;                  \
        __builtin_amdgcn_global_load_lds(                                            \
            (const __attribute__((address_space(1))) unsigned*)g0_,                  \
            (__attribute__((address_space(3))) unsigned*)(ftile_b + (NB_) + wbase),  \
            16, 0, 0);                                                               \
        __builtin_amdgcn_global_load_lds(                                            \
            (const __attribute__((address_space(1))) unsigned*)(g0_ + (size_t)16*NHW), \
            (__attribute__((address_space(3))) unsigned*)(ftile_b + (NB_) + 8192 + wbase), \
            16, 0, 0);                                                               \
    } while (0)

    // prologue: tiles 0 and 1 in flight (4 outstanding ops/thread)
    STAGE(0, 0);
    STAGE(1, 16384);

    #pragma unroll
    for (int c0 = 0; c0 < 8; ++c0) {
        if (c0 < 7) {
            asm volatile("s_waitcnt vmcnt(2)" ::: "memory");  // tile c0 landed (oldest 2)
        } else {
            asm volatile("s_waitcnt vmcnt(0)" ::: "memory");  // last tile: drain
        }
        __builtin_amdgcn_sched_barrier(0);
        __builtin_amdgcn_s_barrier();          // every thread's cur-tile loads landed;
                                               // also: all waves done compute(c0-1)
        __builtin_amdgcn_sched_barrier(0);     // rule #18: no ds_read hoisting above

        if (c0 < 6) STAGE(c0 + 2, ((c0 + 2) % 3) * 16384);   // safe: last reader was
                                                             // compute(c0-1), fenced above
        const float* ft = ftile[c0 % 3];
        union { unsigned u[2]; long long ll; } bc;
        bc.u[0] = fp8x4_from_f32(ft[(cq+0)*128 + pl], ft[(cq+1)*128 + pl],
                                 ft[(cq+2)*128 + pl], ft[(cq+3)*128 + pl]);
        bc.u[1] = fp8x4_from_f32(ft[(cq+4)*128 + pl], ft[(cq+5)*128 + pl],
                                 ft[(cq+6)*128 + pl], ft[(cq+7)*128 + pl]);
        #pragma unroll
        for (int dt = 0; dt < 8; ++dt) {
            union { unsigned u[2]; long long ll; } af;
            af.u[0] = *(const unsigned*)&awp8[((dt*8 + c0)*64 + lane)*8];
            af.u[1] = *(const unsigned*)&awp8[((dt*8 + c0)*64 + lane)*8 + 4];
            acc[dt] = __builtin_amdgcn_mfma_f32_16x16x32_fp8_fp8(af.ll, bc.ll, acc[dt], 0, 0, 0);
        }
    }
#undef STAGE

    // ---- epilogue: LDS transpose -> fully coalesced vm stores ----
    // Writes buf0 only; its last reader was compute(6), fenced by barrier 7.
    {
        unsigned* lw = (unsigned*)ftile;
        const int sw = (pl & 7) << 2;   // XOR swizzle: 2-way write conflict (free)
        #pragma unroll
        for (int dt = 0; dt < 8; ++dt) {
            floatx4 v = acc[dt];
            lw[pl*32 + ((dt*4 + q) ^ sw)] = fp8x4_from_f32(v[0], v[1], v[2], v[3]);
        }
    }
    __syncthreads();
    {
        unsigned char* vmbase = vm + ((size_t)(b*NHW + slot*128))*ND;
        const unsigned* lr = (const unsigned*)ftile;
        #pragma unroll
        for (int k = 0; k < 2; ++k) {
            const int px  = (t >> 3) + k*64;
            const int w8b = (t & 7) * 4;
            uint4 vv = *(const uint4*)&lr[px*32 + (w8b ^ ((px & 7) << 2))];
            *(uint4*)(vmbase + k*8192 + t*16) = vv;   // 512thr x 16B x2: contiguous
        }
    }
}

// Gather (spatially bucketed, L1-resident vm patch) + MFMA MLP.
// Queue-free: block = (bkt, chunk) from blockIdx; empty chunks exit on a
// cached counts load; 3072-slot grid >> 512 resident -> HW backfill balances.
__global__ __launch_bounds__(512, 4)
void gather_mlp(const unsigned char* __restrict__ vm, const float* __restrict__ coords,
                const int* __restrict__ counts, const int* __restrict__ order,
                const unsigned short* __restrict__ W1bf, const float* __restrict__ b1,
                const float* __restrict__ W2, const float* __restrict__ b2,
                float* __restrict__ out)
{
    __shared__ unsigned short feat[64 * FS];
    __shared__ float part[64][8];
    __shared__ float W2s[256];   // (e -> [W2[0][e], W2[1][e]])
    __shared__ float b1s[128];
    __shared__ int gidx[64];

    const int bkt = blockIdx.x & 1023;
    const int c   = blockIdx.x >> 10;
    const int n   = min(counts[bkt*CSTRIDE], CAP);
    const int np  = min(n - c*64, 64);
    if (np <= 0) return;
    const int t   = threadIdx.x;

    if (t < 128) {
        W2s[t*2]   = W2[t];
        W2s[t*2+1] = W2[ND + t];
        b1s[t]     = b1[t];
    }

    // ---- Phase A: gather. 8 threads/pt, 16 fp8 channels each. ----
    {
        const int pt = t >> 3;
        const int c8 = t & 7;
        if (pt < np) {
            const int g = order[bkt*CAP + c*64 + pt];
            if (c8 == 0) gidx[pt] = g;
            const int b = g >> 14;
            const float cx = coords[(size_t)g*2 + 0];
            const float cy = coords[(size_t)g*2 + 1];
            const float ix = cx * (float)(NW - 1);
            const float iy = cy * (float)(NH - 1);
            const float x0f = floorf(ix), y0f = floorf(iy);
            const int x0 = (int)x0f, y0 = (int)y0f;
            const float wx1 = ix - x0f, wy1 = iy - y0f;
            const float wxv[4] = {1.f - wx1, 1.f, 1.f, wx1};
            const float wyv[4] = {1.f - wy1, 1.f, 1.f, wy1};
            floatx2 acc[8];
            #pragma unroll
            for (int k = 0; k < 8; ++k) acc[k] = (floatx2)(0.f);
            const unsigned char* vmb = vm + (size_t)b*NHW*ND + c8*16;
            #pragma unroll
            for (int j = 0; j < 4; ++j) {
                const int Y  = y0 - 1 + j;
                const int Yc = min(max(Y, 0), NH-1);
                const bool vy = (Y >= 0) & (Y < NH);
                #pragma unroll
                for (int i = 0; i < 4; ++i) {
                    const int X  = x0 - 1 + i;
                    const int Xc = min(max(X, 0), NW-1);
                    const bool vx = (X >= 0) & (X < NW);
                    const float wgt = (vx & vy) ? wxv[i]*wyv[j] : 0.f;
                    uint4 u = *(const uint4*)(vmb + (size_t)(Yc*NW + Xc)*ND);
                    const floatx2 w2 = {wgt, wgt};
                    acc[0] += w2 * fp8x2_to_f32<false>(u.x);
                    acc[1] += w2 * fp8x2_to_f32<true >(u.x);
                    acc[2] += w2 * fp8x2_to_f32<false>(u.y);
                    acc[3] += w2 * fp8x2_to_f32<true >(u.y);
                    acc[4] += w2 * fp8x2_to_f32<false>(u.z);
                    acc[5] += w2 * fp8x2_to_f32<true >(u.z);
                    acc[6] += w2 * fp8x2_to_f32<false>(u.w);
                    acc[7] += w2 * fp8x2_to_f32<true >(u.w);
                }
            }
            const float s9 = 1.f/9.f;
            unsigned pk[8];
            #pragma unroll
            for (int k = 0; k < 8; ++k)
                pk[k] = pk_bf16(acc[k].x*s9, acc[k].y*s9);
            *(uint4*)&feat[pt*FS + c8*16]     = make_uint4(pk[0],pk[1],pk[2],pk[3]);
            *(uint4*)&feat[pt*FS + c8*16 + 8] = make_uint4(pk[4],pk[5],pk[6],pk[7]);
        }
    }
    __syncthreads();

    // ---- Phase B: MFMA MLP. wave w: e-pair mp=w&3, pt-pair npr=w>>2. ----
    {
        const int lane = t & 63;
        const int w    = t >> 6;
        const int l15  = lane & 15;
        const int q    = lane >> 4;
        const int mp   = w & 3;
        const int npr  = w >> 2;

        if (npr*32 < np) {   // skip waves whose pt-tile is entirely past np
            floatx4 C[2][2];
            #pragma unroll
            for (int mi = 0; mi < 2; ++mi)
                #pragma unroll
                for (int ni = 0; ni < 2; ++ni) C[mi][ni] = (floatx4)(0.f);

            #pragma unroll
            for (int kk = 0; kk < 4; ++kk) {
                short8 a0 = *(const short8*)&W1bf[((mp*2+0)*16 + l15)*ND + kk*32 + q*8];
                short8 a1 = *(const short8*)&W1bf[((mp*2+1)*16 + l15)*ND + kk*32 + q*8];
                short8 f0 = *(const short8*)&feat[((npr*2+0)*16 + l15)*FS + kk*32 + q*8];
                short8 f1 = *(const short8*)&feat[((npr*2+1)*16 + l15)*FS + kk*32 + q*8];
                C[0][0] = __builtin_amdgcn_mfma_f32_16x16x32_bf16(a0, f0, C[0][0], 0, 0, 0);
                C[0][1] = __builtin_amdgcn_mfma_f32_16x16x32_bf16(a0, f1, C[0][1], 0, 0, 0);
                C[1][0] = __builtin_amdgcn_mfma_f32_16x16x32_bf16(a1, f0, C[1][0], 0, 0, 0);
                C[1][1] = __builtin_amdgcn_mfma_f32_16x16x32_bf16(a1, f1, C[1][1], 0, 0, 0);
            }
            // epilogue: e = (mp*2+mi)*16 + q*4 + reg ; pt = (npr*2+ni)*16 + l15
            #pragma unroll
            for (int ni = 0; ni < 2; ++ni) {
                float s0 = 0.f, s1 = 0.f;
                #pragma unroll
                for (int mi = 0; mi < 2; ++mi) {
                    const int e0 = (mp*2 + mi)*16 + q*4;
                    float4 bq = *(const float4*)&b1s[e0];
                    floatx4 h4 = C[mi][ni];
                    #pragma unroll
                    for (int r = 0; r < 4; ++r) {
                        float hv = fmaxf(h4[r] + (&bq.x)[r], 0.f);
                        float2 wv = *(const float2*)&W2s[(e0 + r)*2];
                        s0 = fmaf(hv, wv.x, s0);
                        s1 = fmaf(hv, wv.y, s1);
                    }
                }
                s0 += __shfl_xor(s0, 16); s0 += __shfl_xor(s0, 32);
                s1 += __shfl_xor(s1, 16); s1 += __shfl_xor(s1, 32);
                if (q == 0) {
                    const int pt = (npr*2 + ni)*16 + l15;
                    part[pt][mp*2 + 0] = s0;
                    part[pt][mp*2 + 1] = s1;
                }
            }
        }
    }
    __syncthreads();

    // ---- Phase C: reduce 4 e-pairs, tanh, scatter-write ----
    if (t < np) {
        const int g = gidx[t];
        float s0 = part[t][0] + part[t][2] + part[t][4] + part[t][6];
        float s1 = part[t][1] + part[t][3] + part[t][5] + part[t][7];
        const float cx = coords[(size_t)g*2 + 0];
        const float cy = coords[(size_t)g*2 + 1];
        const float MD = 0.5f / 512.0f;
        float2 o = make_float2(cx + tanhf(s0 + b2[0]) * MD,
                               cy + tanhf(s1 + b2[1]) * MD);
        *(float2*)&out[(size_t)g*2] = o;
    }
}

extern "C" void kernel_launch(void* const* d_in, const int* in_sizes, int n_in,
                              void* d_out, int out_size, void* d_ws, size_t ws_size,
                              hipStream_t stream)
{
    const float* fmap   = (const float*)d_in[0];
    const float* coords = (const float*)d_in[1];
    const float* Wp     = (const float*)d_in[2];
    const float* W1     = (const float*)d_in[3];
    const float* b1     = (const float*)d_in[4];
    const float* W2     = (const float*)d_in[5];
    const float* b2     = (const float*)d_in[6];
    float* out = (float*)d_out;

    // ws layout
    unsigned char* vm = (unsigned char*)d_ws;                         // 8 MB fp8
    char* base = (char*)d_ws + (size_t)NB*NHW*ND;
    unsigned short* W1bf = (unsigned short*)base;                     // 32 KB bf16
    unsigned char* Wpbf8 = (unsigned char*)(base + 32768);            // 32 KB fp8 frags
    int* counts = (int*)(base + 65536);                               // 64 KB (padded)
    int* order  = (int*)(base + 65536 + 65536);                       // 768 KB

    prep_kernel<<<dim3(64),   512, 0, stream>>>(Wp, W1, counts, W1bf, Wpbf8);
    proj_fused <<<dim3(512),  512, 0, stream>>>(fmap, coords, Wpbf8,
                                                counts, order, vm);
    gather_mlp <<<dim3(GGRID),512, 0, stream>>>(vm, coords, counts, order,
                                                W1bf, b1, W2, b2, out);
}

// Round 15
// 129.573 us; speedup vs baseline: 1.0122x; 1.0122x over previous
//
#include <hip/hip_runtime.h>
#include <cstddef>

#define NB 4
#define NC 256
#define ND 128
#define NH 128
#define NW 128
#define NHW (NH*NW)
#define NT 16384
#define NBKT 1024   // 4 batches x 16x16 tiles of 8x8 px
#define CAP 192     // per-bucket capacity (mean 64, P(>192) ~ e^-64: never)
#define FS 136      // feat row stride in ushorts
#define GGRID 3072  // NBKT * ceil(CAP/64) chunk slots
#define CSTRIDE 16  // counts padded to 1 counter / 64B line (atomic contention fix)

typedef short   short8  __attribute__((ext_vector_type(8)));
typedef unsigned short ushort8 __attribute__((ext_vector_type(8)));
typedef float   floatx4 __attribute__((ext_vector_type(4)));
typedef float   floatx2 __attribute__((ext_vector_type(2)));

__device__ __forceinline__ unsigned pk_bf16(float a, float b) {
    unsigned ua = __float_as_uint(a);
    unsigned ub = __float_as_uint(b);
    ua += 0x7fffu + ((ua >> 16) & 1u);
    ub += 0x7fffu + ((ub >> 16) & 1u);
    return (ua >> 16) | (ub & 0xffff0000u);
}

// ---- fp8 e4m3 (OCP) HW cvt ----
__device__ __forceinline__ unsigned fp8x4_from_f32(float v0, float v1, float v2, float v3) {
    int r = 0;
    r = __builtin_amdgcn_cvt_pk_fp8_f32(v0, v1, r, false);
    r = __builtin_amdgcn_cvt_pk_fp8_f32(v2, v3, r, true);
    return (unsigned)r;
}
template <bool HI>
__device__ __forceinline__ floatx2 fp8x2_to_f32(unsigned w) {
    return __builtin_amdgcn_cvt_pk_f32_fp8((int)w, HI);
}

__device__ __forceinline__ int bucket_of(float cx, float cy, int b) {
    int x0 = (int)floorf(cx * (float)(NW - 1));
    int y0 = (int)floorf(cy * (float)(NH - 1));
    x0 = min(max(x0, 0), NW - 1);
    y0 = min(max(y0, 0), NH - 1);
    return b * 256 + (y0 >> 3) * 16 + (x0 >> 3);
}

// Prep: zero counts + pack W1->bf16 + pack Wp->fp8 A-fragments ONCE (R13:
// killed 67MB of per-block Wp re-reads, -6us).
__global__ __launch_bounds__(512)
void prep_kernel(const float* __restrict__ Wp, const float* __restrict__ W1,
                 int* __restrict__ counts, unsigned short* __restrict__ W1bf,
                 unsigned char* __restrict__ Wpbf8)
{
    const int gid = blockIdx.x * 512 + threadIdx.x;   // [0, 32768)
    if (gid < NBKT*CSTRIDE) counts[gid] = 0;
    if (gid < 16384) {
        unsigned u = __float_as_uint(W1[gid]);
        u += 0x7fffu + ((u >> 16) & 1u);
        W1bf[gid] = (unsigned short)(u >> 16);
    }
    if (gid < 4096) {   // fragment idx = (dt*8 + ch)*64 + lane
        const int lane = gid & 63;
        const int ch   = (gid >> 6) & 7;
        const int dt   = gid >> 9;
        const int l15  = lane & 15;
        const int q    = lane >> 4;
        const float* src = Wp + (size_t)(dt*16 + l15)*NC + ch*32 + q*8;
        float4 g0 = *(const float4*)src;
        float4 g1 = *(const float4*)(src + 4);
        uint2 pk = make_uint2(fp8x4_from_f32(g0.x,g0.y,g0.z,g0.w),
                              fp8x4_from_f32(g1.x,g1.y,g1.z,g1.w));
        *(uint2*)&Wpbf8[(size_t)gid*8] = pk;
    }
}

// Fused: binning prelude, then vm projection (fp8 MFMA, double-buffered LDS
// pipeline with counted vmcnt(2)). awp8 staged by 32KB linear copy from the
// pre-packed global fragments. R13 exact form (best measured: 130.1us;
// R14's 3-buffer variant was neutral-to-negative, reverted).
__global__ __launch_bounds__(512, 4)
void proj_fused(const float* __restrict__ fmap, const float* __restrict__ coords,
                const unsigned char* __restrict__ Wpbf8,
                int* __restrict__ counts, int* __restrict__ order,
                unsigned char* __restrict__ vm)
{
    const int bi = blockIdx.x;
    const int t  = threadIdx.x;

    // ---- prelude: bin 128 coords (t<128) ----
    if (t < 128) {
        const int g = bi * 128 + t;              // [0, 65536)
        const float cx = coords[(size_t)g*2 + 0];
        const float cy = coords[(size_t)g*2 + 1];
        const int bkt = bucket_of(cx, cy, g >> 14);
        const int pos = atomicAdd(&counts[bkt*CSTRIDE], 1);
        if (pos < CAP) order[bkt*CAP + pos] = g;
    }

    __shared__ unsigned char awp8[8*8*64*8];   // 32 KB fp8 A-fragments
    __shared__ float ftile[2][32*128];         // 2 x 16 KB ping-pong fmap tiles

    const int lane = t & 63;
    const int w    = t >> 6;
    const int l15  = lane & 15;
    const int q    = lane >> 4;
    const int cq   = q * 8;

    {   // stage pre-packed A-fragments: 32 KB linear copy
        const uint4* src = (const uint4*)Wpbf8;
        uint4* dst = (uint4*)awp8;
        #pragma unroll
        for (int i = 0; i < 4; ++i) dst[t + i*512] = src[t + i*512];
    }

    const int b    = (bi & 7) >> 1;
    const int slot = ((bi >> 3) << 1) | (bi & 1);
    const int pl   = w*16 + l15;                 // local pixel 0..127

    // staging geometry: 32 threads per 512B channel row, 16 rows per call
    const int row_thr = t >> 5;                  // 0..15
    const int px_off  = (t & 31) * 4;            // 0..124
    const float* gstage = fmap + (size_t)b*NC*NHW + slot*128 + px_off;
    char* ftile_b = (char*)ftile;
    const unsigned wbase = (unsigned)((t >> 6) * 1024);  // wave-uniform dest base

    floatx4 acc[8];
    #pragma unroll
    for (int i = 0; i < 8; ++i) acc[i] = (floatx4)(0.f);

    __syncthreads();   // awp copy + prelude drained

    // issue step-0 tile into buf 0 (2 outstanding vmem ops/thread)
    {
        const float* g0 = gstage + (size_t)(0*32 + row_thr)*NHW;
        __builtin_amdgcn_global_load_lds(
            (const __attribute__((address_space(1))) unsigned*)g0,
            (__attribute__((address_space(3))) unsigned*)(ftile_b + wbase), 16, 0, 0);
        __builtin_amdgcn_global_load_lds(
            (const __attribute__((address_space(1))) unsigned*)(g0 + (size_t)16*NHW),
            (__attribute__((address_space(3))) unsigned*)(ftile_b + 8192 + wbase), 16, 0, 0);
    }

    #pragma unroll
    for (int c0 = 0; c0 < 8; ++c0) {
        // issue next tile into the other buffer (freed by prev iter's barrier)
        if (c0 < 7) {
            const unsigned nb = (unsigned)(((c0+1) & 1) * 16384);
            const float* g0 = gstage + (size_t)((c0+1)*32 + row_thr)*NHW;
            __builtin_amdgcn_global_load_lds(
                (const __attribute__((address_space(1))) unsigned*)g0,
                (__attribute__((address_space(3))) unsigned*)(ftile_b + nb + wbase), 16, 0, 0);
            __builtin_amdgcn_global_load_lds(
                (const __attribute__((address_space(1))) unsigned*)(g0 + (size_t)16*NHW),
                (__attribute__((address_space(3))) unsigned*)(ftile_b + nb + 8192 + wbase), 16, 0, 0);
            asm volatile("s_waitcnt vmcnt(2)" ::: "memory");  // cur tile (FIFO oldest 2) landed
        } else {
            asm volatile("s_waitcnt vmcnt(0)" ::: "memory");  // last tile: drain
        }
        __builtin_amdgcn_sched_barrier(0);
        __builtin_amdgcn_s_barrier();          // every thread's cur-tile loads landed
        __builtin_amdgcn_sched_barrier(0);     // rule #18: no ds_read hoisting above

        const float* ft = ftile[c0 & 1];
        union { unsigned u[2]; long long ll; } bc;
        bc.u[0] = fp8x4_from_f32(ft[(cq+0)*128 + pl], ft[(cq+1)*128 + pl],
                                 ft[(cq+2)*128 + pl], ft[(cq+3)*128 + pl]);
        bc.u[1] = fp8x4_from_f32(ft[(cq+4)*128 + pl], ft[(cq+5)*128 + pl],
                                 ft[(cq+6)*128 + pl], ft[(cq+7)*128 + pl]);
        #pragma unroll
        for (int dt = 0; dt < 8; ++dt) {
            union { unsigned u[2]; long long ll; } af;
            af.u[0] = *(const unsigned*)&awp8[((dt*8 + c0)*64 + lane)*8];
            af.u[1] = *(const unsigned*)&awp8[((dt*8 + c0)*64 + lane)*8 + 4];
            acc[dt] = __builtin_amdgcn_mfma_f32_16x16x32_fp8_fp8(af.ll, bc.ll, acc[dt], 0, 0, 0);
        }
        __builtin_amdgcn_s_barrier();          // all waves done reading this buffer
    }

    // ---- epilogue: LDS transpose -> fully coalesced vm stores ----
    {
        unsigned* lw = (unsigned*)ftile;
        const int sw = (pl & 7) << 2;   // XOR swizzle: 2-way write conflict (free)
        #pragma unroll
        for (int dt = 0; dt < 8; ++dt) {
            floatx4 v = acc[dt];
            lw[pl*32 + ((dt*4 + q) ^ sw)] = fp8x4_from_f32(v[0], v[1], v[2], v[3]);
        }
    }
    __syncthreads();
    {
        unsigned char* vmbase = vm + ((size_t)(b*NHW + slot*128))*ND;
        const unsigned* lr = (const unsigned*)ftile;
        #pragma unroll
        for (int k = 0; k < 2; ++k) {
            const int px  = (t >> 3) + k*64;
            const int w8b = (t & 7) * 4;
            uint4 vv = *(const uint4*)&lr[px*32 + (w8b ^ ((px & 7) << 2))];
            *(uint4*)(vmbase + k*8192 + t*16) = vv;   // 512thr x 16B x2: contiguous
        }
    }
}

// Gather (spatially bucketed, L1-resident vm patch) + MFMA MLP.
// R15: __launch_bounds__(512,8) -> VGPR cap 64 -> 8 waves/SIMD -> 4 blocks/CU
// (was 2). Gather is latency-bound (~18us vs ~4us VALU floor; first-touch vm
// reads are cross-XCD L2/L3); doubling resident waves doubles latency hiding.
__global__ __launch_bounds__(512, 8)
void gather_mlp(const unsigned char* __restrict__ vm, const float* __restrict__ coords,
                const int* __restrict__ counts, const int* __restrict__ order,
                const unsigned short* __restrict__ W1bf, const float* __restrict__ b1,
                const float* __restrict__ W2, const float* __restrict__ b2,
                float* __restrict__ out)
{
    __shared__ unsigned short feat[64 * FS];
    __shared__ float part[64][8];
    __shared__ float W2s[256];   // (e -> [W2[0][e], W2[1][e]])
    __shared__ float b1s[128];
    __shared__ int gidx[64];

    const int bkt = blockIdx.x & 1023;
    const int c   = blockIdx.x >> 10;
    const int n   = min(counts[bkt*CSTRIDE], CAP);
    const int np  = min(n - c*64, 64);
    if (np <= 0) return;
    const int t   = threadIdx.x;

    if (t < 128) {
        W2s[t*2]   = W2[t];
        W2s[t*2+1] = W2[ND + t];
        b1s[t]     = b1[t];
    }

    // ---- Phase A: gather. 8 threads/pt, 16 fp8 channels each. ----
    {
        const int pt = t >> 3;
        const int c8 = t & 7;
        if (pt < np) {
            const int g = order[bkt*CAP + c*64 + pt];
            if (c8 == 0) gidx[pt] = g;
            const int b = g >> 14;
            const float cx = coords[(size_t)g*2 + 0];
            const float cy = coords[(size_t)g*2 + 1];
            const float ix = cx * (float)(NW - 1);
            const float iy = cy * (float)(NH - 1);
            const float x0f = floorf(ix), y0f = floorf(iy);
            const int x0 = (int)x0f, y0 = (int)y0f;
            const float wx1 = ix - x0f, wy1 = iy - y0f;
            const float wxv[4] = {1.f - wx1, 1.f, 1.f, wx1};
            const float wyv[4] = {1.f - wy1, 1.f, 1.f, wy1};
            floatx2 acc[8];
            #pragma unroll
            for (int k = 0; k < 8; ++k) acc[k] = (floatx2)(0.f);
            const unsigned char* vmb = vm + (size_t)b*NHW*ND + c8*16;
            #pragma unroll
            for (int j = 0; j < 4; ++j) {
                const int Y  = y0 - 1 + j;
                const int Yc = min(max(Y, 0), NH-1);
                const bool vy = (Y >= 0) & (Y < NH);
                #pragma unroll
                for (int i = 0; i < 4; ++i) {
                    const int X  = x0 - 1 + i;
                    const int Xc = min(max(X, 0), NW-1);
                    const bool vx = (X >= 0) & (X < NW);
                    const float wgt = (vx & vy) ? wxv[i]*wyv[j] : 0.f;
                    uint4 u = *(const uint4*)(vmb + (size_t)(Yc*NW + Xc)*ND);
                    const floatx2 w2 = {wgt, wgt};
                    acc[0] += w2 * fp8x2_to_f32<false>(u.x);
                    acc[1] += w2 * fp8x2_to_f32<true >(u.x);
                    acc[2] += w2 * fp8x2_to_f32<false>(u.y);
                    acc[3] += w2 * fp8x2_to_f32<true >(u.y);
                    acc[4] += w2 * fp8x2_to_f32<false>(u.z);
                    acc[5] += w2 * fp8x2_to_f32<true >(u.z);
                    acc[6] += w2 * fp8x2_to_f32<false>(u.w);
                    acc[7] += w2 * fp8x2_to_f32<true >(u.w);
                }
            }
            const float s9 = 1.f/9.f;
            unsigned pk[8];
            #pragma unroll
            for (int k = 0; k < 8; ++k)
                pk[k] = pk_bf16(acc[k].x*s9, acc[k].y*s9);
            *(uint4*)&feat[pt*FS + c8*16]     = make_uint4(pk[0],pk[1],pk[2],pk[3]);
            *(uint4*)&feat[pt*FS + c8*16 + 8] = make_uint4(pk[4],pk[5],pk[6],pk[7]);
        }
    }
    __syncthreads();

    // ---- Phase B: MFMA MLP. wave w: e-pair mp=w&3, pt-pair npr=w>>2. ----
    {
        const int lane = t & 63;
        const int w    = t >> 6;
        const int l15  = lane & 15;
        const int q    = lane >> 4;
        const int mp   = w & 3;
        const int npr  = w >> 2;

        if (npr*32 < np) {   // skip waves whose pt-tile is entirely past np
            floatx4 C[2][2];
            #pragma unroll
            for (int mi = 0; mi < 2; ++mi)
                #pragma unroll
                for (int ni = 0; ni < 2; ++ni) C[mi][ni] = (floatx4)(0.f);

            #pragma unroll
            for (int kk = 0; kk < 4; ++kk) {
                short8 a0 = *(const short8*)&W1bf[((mp*2+0)*16 + l15)*ND + kk*32 + q*8];
                short8 a1 = *(const short8*)&W1bf[((mp*2+1)*16 + l15)*ND + kk*32 + q*8];
                short8 f0 = *(const short8*)&feat[((npr*2+0)*16 + l15)*FS + kk*32 + q*8];
                short8 f1 = *(const short8*)&feat[((npr*2+1)*16 + l15)*FS + kk*32 + q*8];
                C[0][0] = __builtin_amdgcn_mfma_f32_16x16x32_bf16(a0, f0, C[0][0], 0, 0, 0);
                C[0][1] = __builtin_amdgcn_mfma_f32_16x16x32_bf16(a0, f1, C[0][1], 0, 0, 0);
                C[1][0] = __builtin_amdgcn_mfma_f32_16x16x32_bf16(a1, f0, C[1][0], 0, 0, 0);
                C[1][1] = __builtin_amdgcn_mfma_f32_16x16x32_bf16(a1, f1, C[1][1], 0, 0, 0);
            }
            // epilogue: e = (mp*2+mi)*16 + q*4 + reg ; pt = (npr*2+ni)*16 + l15
            #pragma unroll
            for (int ni = 0; ni < 2; ++ni) {
                float s0 = 0.f, s1 = 0.f;
                #pragma unroll
                for (int mi = 0; mi < 2; ++mi) {
                    const int e0 = (mp*2 + mi)*16 + q*4;
                    float4 bq = *(const float4*)&b1s[e0];
                    floatx4 h4 = C[mi][ni];
                    #pragma unroll
                    for (int r = 0; r < 4; ++r) {
                        float hv = fmaxf(h4[r] + (&bq.x)[r], 0.f);
                        float2 wv = *(const float2*)&W2s[(e0 + r)*2];
                        s0 = fmaf(hv, wv.x, s0);
                        s1 = fmaf(hv, wv.y, s1);
                    }
                }
                s0 += __shfl_xor(s0, 16); s0 += __shfl_xor(s0, 32);
                s1 += __shfl_xor(s1, 16); s1 += __shfl_xor(s1, 32);
                if (q == 0) {
                    const int pt = (npr*2 + ni)*16 + l15;
                    part[pt][mp*2 + 0] = s0;
                    part[pt][mp*2 + 1] = s1;
                }
            }
        }
    }
    __syncthreads();

    // ---- Phase C: reduce 4 e-pairs, tanh, scatter-write ----
    if (t < np) {
        const int g = gidx[t];
        float s0 = part[t][0] + part[t][2] + part[t][4] + part[t][6];
        float s1 = part[t][1] + part[t][3] + part[t][5] + part[t][7];
        const float cx = coords[(size_t)g*2 + 0];
        const float cy = coords[(size_t)g*2 + 1];
        const float MD = 0.5f / 512.0f;
        float2 o = make_float2(cx + tanhf(s0 + b2[0]) * MD,
                               cy + tanhf(s1 + b2[1]) * MD);
        *(float2*)&out[(size_t)g*2] = o;
    }
}

extern "C" void kernel_launch(void* const* d_in, const int* in_sizes, int n_in,
                              void* d_out, int out_size, void* d_ws, size_t ws_size,
                              hipStream_t stream)
{
    const float* fmap   = (const float*)d_in[0];
    const float* coords = (const float*)d_in[1];
    const float* Wp     = (const float*)d_in[2];
    const float* W1     = (const float*)d_in[3];
    const float* b1     = (const float*)d_in[4];
    const float* W2     = (const float*)d_in[5];
    const float* b2     = (const float*)d_in[6];
    float* out = (float*)d_out;

    // ws layout
    unsigned char* vm = (unsigned char*)d_ws;                         // 8 MB fp8
    char* base = (char*)d_ws + (size_t)NB*NHW*ND;
    unsigned short* W1bf = (unsigned short*)base;                     // 32 KB bf16
    unsigned char* Wpbf8 = (unsigned char*)(base + 32768);            // 32 KB fp8 frags
    int* counts = (int*)(base + 65536);                               // 64 KB (padded)
    int* order  = (int*)(base + 65536 + 65536);                       // 768 KB

    prep_kernel<<<dim3(64),   512, 0, stream>>>(Wp, W1, counts, W1bf, Wpbf8);
    proj_fused <<<dim3(512),  512, 0, stream>>>(fmap, coords, Wpbf8,
                                                counts, order, vm);
    gather_mlp <<<dim3(GGRID),512, 0, stream>>>(vm, coords, counts, order,
                                                W1bf, b1, W2, b2, out);
}

// Round 16
// 129.087 us; speedup vs baseline: 1.0160x; 1.0038x over previous
//
#include <hip/hip_runtime.h>
#include <cstddef>

#define NB 4
#define NC 256
#define ND 128
#define NH 128
#define NW 128
#define NHW (NH*NW)
#define NT 16384
#define NBKT 1024   // 4 batches x 16x16 tiles of 8x8 px
#define CAP 192     // per-bucket capacity (mean 64, P(>192) ~ e^-64: never)
#define FS 136      // feat row stride in ushorts
#define GGRID 3072  // NBKT * ceil(CAP/64) chunk slots
#define CSTRIDE 16  // counts padded to 1 counter / 64B line (atomic contention fix)

typedef short   short8  __attribute__((ext_vector_type(8)));
typedef unsigned short ushort8 __attribute__((ext_vector_type(8)));
typedef float   floatx4 __attribute__((ext_vector_type(4)));
typedef float   floatx2 __attribute__((ext_vector_type(2)));

__device__ __forceinline__ unsigned pk_bf16(float a, float b) {
    unsigned ua = __float_as_uint(a);
    unsigned ub = __float_as_uint(b);
    ua += 0x7fffu + ((ua >> 16) & 1u);
    ub += 0x7fffu + ((ub >> 16) & 1u);
    return (ua >> 16) | (ub & 0xffff0000u);
}

// ---- fp8 e4m3 (OCP) HW cvt ----
__device__ __forceinline__ unsigned fp8x4_from_f32(float v0, float v1, float v2, float v3) {
    int r = 0;
    r = __builtin_amdgcn_cvt_pk_fp8_f32(v0, v1, r, false);
    r = __builtin_amdgcn_cvt_pk_fp8_f32(v2, v3, r, true);
    return (unsigned)r;
}
template <bool HI>
__device__ __forceinline__ floatx2 fp8x2_to_f32(unsigned w) {
    return __builtin_amdgcn_cvt_pk_f32_fp8((int)w, HI);
}

__device__ __forceinline__ int bucket_of(float cx, float cy, int b) {
    int x0 = (int)floorf(cx * (float)(NW - 1));
    int y0 = (int)floorf(cy * (float)(NH - 1));
    x0 = min(max(x0, 0), NW - 1);
    y0 = min(max(y0, 0), NH - 1);
    return b * 256 + (y0 >> 3) * 16 + (x0 >> 3);
}

// Prep: zero counts + pack W1->bf16 + pack Wp->fp8 A-fragments ONCE (R13:
// killed 67MB of per-block Wp re-reads, -6us).
__global__ __launch_bounds__(512)
void prep_kernel(const float* __restrict__ Wp, const float* __restrict__ W1,
                 int* __restrict__ counts, unsigned short* __restrict__ W1bf,
                 unsigned char* __restrict__ Wpbf8)
{
    const int gid = blockIdx.x * 512 + threadIdx.x;   // [0, 32768)
    if (gid < NBKT*CSTRIDE) counts[gid] = 0;
    if (gid < 16384) {
        unsigned u = __float_as_uint(W1[gid]);
        u += 0x7fffu + ((u >> 16) & 1u);
        W1bf[gid] = (unsigned short)(u >> 16);
    }
    if (gid < 4096) {   // fragment idx = (dt*8 + ch)*64 + lane
        const int lane = gid & 63;
        const int ch   = (gid >> 6) & 7;
        const int dt   = gid >> 9;
        const int l15  = lane & 15;
        const int q    = lane >> 4;
        const float* src = Wp + (size_t)(dt*16 + l15)*NC + ch*32 + q*8;
        float4 g0 = *(const float4*)src;
        float4 g1 = *(const float4*)(src + 4);
        uint2 pk = make_uint2(fp8x4_from_f32(g0.x,g0.y,g0.z,g0.w),
                              fp8x4_from_f32(g1.x,g1.y,g1.z,g1.w));
        *(uint2*)&Wpbf8[(size_t)gid*8] = pk;
    }
}

// Fused: binning prelude, then vm projection (fp8 MFMA, double-buffered LDS
// pipeline with counted vmcnt(2)). R16: XCD-banded row mapping -- each 16-row
// band of vm is written entirely by blocks on ONE XCD (bi%8), so gather
// blocks mapped to the same XCD read producer-local L2 instead of cross-XCD
// L3 (dispatch round-robins blockIdx over XCDs).
__global__ __launch_bounds__(512, 4)
void proj_fused(const float* __restrict__ fmap, const float* __restrict__ coords,
                const unsigned char* __restrict__ Wpbf8,
                int* __restrict__ counts, int* __restrict__ order,
                unsigned char* __restrict__ vm)
{
    const int bi = blockIdx.x;
    const int t  = threadIdx.x;

    // ---- prelude: bin 128 coords (t<128) ----
    if (t < 128) {
        const int g = bi * 128 + t;              // [0, 65536)
        const float cx = coords[(size_t)g*2 + 0];
        const float cy = coords[(size_t)g*2 + 1];
        const int bkt = bucket_of(cx, cy, g >> 14);
        const int pos = atomicAdd(&counts[bkt*CSTRIDE], 1);
        if (pos < CAP) order[bkt*CAP + pos] = g;
    }

    __shared__ unsigned char awp8[8*8*64*8];   // 32 KB fp8 A-fragments
    __shared__ float ftile[2][32*128];         // 2 x 16 KB ping-pong fmap tiles

    const int lane = t & 63;
    const int w    = t >> 6;
    const int l15  = lane & 15;
    const int q    = lane >> 4;
    const int cq   = q * 8;

    {   // stage pre-packed A-fragments: 32 KB linear copy
        const uint4* src = (const uint4*)Wpbf8;
        uint4* dst = (uint4*)awp8;
        #pragma unroll
        for (int i = 0; i < 4; ++i) dst[t + i*512] = src[t + i*512];
    }

    // XCD-banded row map: band (16 rows) -> one XCD (bijective over 512 rows)
    const int xcd  = bi & 7;
    const int j    = bi >> 3;                    // 0..63
    const int band = xcd + 8*(j >> 4);           // 0..31
    const int grow = band*16 + (j & 15);         // global row 0..511
    const int b    = grow >> 7;
    const int slot = grow & 127;                 // image row
    const int pl   = w*16 + l15;                 // local pixel 0..127

    // staging geometry: 32 threads per 512B channel row, 16 rows per call
    const int row_thr = t >> 5;                  // 0..15
    const int px_off  = (t & 31) * 4;            // 0..124
    const float* gstage = fmap + (size_t)b*NC*NHW + slot*128 + px_off;
    char* ftile_b = (char*)ftile;
    const unsigned wbase = (unsigned)((t >> 6) * 1024);  // wave-uniform dest base

    floatx4 acc[8];
    #pragma unroll
    for (int i = 0; i < 8; ++i) acc[i] = (floatx4)(0.f);

    __syncthreads();   // awp copy + prelude drained

    // issue step-0 tile into buf 0 (2 outstanding vmem ops/thread)
    {
        const float* g0 = gstage + (size_t)(0*32 + row_thr)*NHW;
        __builtin_amdgcn_global_load_lds(
            (const __attribute__((address_space(1))) unsigned*)g0,
            (__attribute__((address_space(3))) unsigned*)(ftile_b + wbase), 16, 0, 0);
        __builtin_amdgcn_global_load_lds(
            (const __attribute__((address_space(1))) unsigned*)(g0 + (size_t)16*NHW),
            (__attribute__((address_space(3))) unsigned*)(ftile_b + 8192 + wbase), 16, 0, 0);
    }

    #pragma unroll
    for (int c0 = 0; c0 < 8; ++c0) {
        // issue next tile into the other buffer (freed by prev iter's barrier)
        if (c0 < 7) {
            const unsigned nb = (unsigned)(((c0+1) & 1) * 16384);
            const float* g0 = gstage + (size_t)((c0+1)*32 + row_thr)*NHW;
            __builtin_amdgcn_global_load_lds(
                (const __attribute__((address_space(1))) unsigned*)g0,
                (__attribute__((address_space(3))) unsigned*)(ftile_b + nb + wbase), 16, 0, 0);
            __builtin_amdgcn_global_load_lds(
                (const __attribute__((address_space(1))) unsigned*)(g0 + (size_t)16*NHW),
                (__attribute__((address_space(3))) unsigned*)(ftile_b + nb + 8192 + wbase), 16, 0, 0);
            asm volatile("s_waitcnt vmcnt(2)" ::: "memory");  // cur tile (FIFO oldest 2) landed
        } else {
            asm volatile("s_waitcnt vmcnt(0)" ::: "memory");  // last tile: drain
        }
        __builtin_amdgcn_sched_barrier(0);
        __builtin_amdgcn_s_barrier();          // every thread's cur-tile loads landed
        __builtin_amdgcn_sched_barrier(0);     // rule #18: no ds_read hoisting above

        const float* ft = ftile[c0 & 1];
        union { unsigned u[2]; long long ll; } bc;
        bc.u[0] = fp8x4_from_f32(ft[(cq+0)*128 + pl], ft[(cq+1)*128 + pl],
                                 ft[(cq+2)*128 + pl], ft[(cq+3)*128 + pl]);
        bc.u[1] = fp8x4_from_f32(ft[(cq+4)*128 + pl], ft[(cq+5)*128 + pl],
                                 ft[(cq+6)*128 + pl], ft[(cq+7)*128 + pl]);
        #pragma unroll
        for (int dt = 0; dt < 8; ++dt) {
            union { unsigned u[2]; long long ll; } af;
            af.u[0] = *(const unsigned*)&awp8[((dt*8 + c0)*64 + lane)*8];
            af.u[1] = *(const unsigned*)&awp8[((dt*8 + c0)*64 + lane)*8 + 4];
            acc[dt] = __builtin_amdgcn_mfma_f32_16x16x32_fp8_fp8(af.ll, bc.ll, acc[dt], 0, 0, 0);
        }
        __builtin_amdgcn_s_barrier();          // all waves done reading this buffer
    }

    // ---- epilogue: LDS transpose -> fully coalesced vm stores ----
    {
        unsigned* lw = (unsigned*)ftile;
        const int sw = (pl & 7) << 2;   // XOR swizzle: 2-way write conflict (free)
        #pragma unroll
        for (int dt = 0; dt < 8; ++dt) {
            floatx4 v = acc[dt];
            lw[pl*32 + ((dt*4 + q) ^ sw)] = fp8x4_from_f32(v[0], v[1], v[2], v[3]);
        }
    }
    __syncthreads();
    {
        unsigned char* vmbase = vm + ((size_t)(b*NHW + slot*128))*ND;
        const unsigned* lr = (const unsigned*)ftile;
        #pragma unroll
        for (int k = 0; k < 2; ++k) {
            const int px  = (t >> 3) + k*64;
            const int w8b = (t & 7) * 4;
            uint4 vv = *(const uint4*)&lr[px*32 + (w8b ^ ((px & 7) << 2))];
            *(uint4*)(vmbase + k*8192 + t*16) = vv;   // 512thr x 16B x2: contiguous
        }
    }
}

// Gather (spatially bucketed) + MFMA MLP.
// R16: blockIdx decodes so the block lands on the XCD whose proj blocks wrote
// this bucket's rows (band = b*8 + ty/2; residue ty>>1 == blockIdx%8): vm
// reads become producer-local L2 hits (~80% of the 4x4+halo window).
__global__ __launch_bounds__(512, 8)
void gather_mlp(const unsigned char* __restrict__ vm, const float* __restrict__ coords,
                const int* __restrict__ counts, const int* __restrict__ order,
                const unsigned short* __restrict__ W1bf, const float* __restrict__ b1,
                const float* __restrict__ W2, const float* __restrict__ b2,
                float* __restrict__ out)
{
    __shared__ unsigned short feat[64 * FS];
    __shared__ float part[64][8];
    __shared__ float W2s[256];   // (e -> [W2[0][e], W2[1][e]])
    __shared__ float b1s[128];
    __shared__ int gidx[64];

    // decode (bkt, chunk) from XCD-aligned blockIdx (bijective over 3072)
    const int v   = blockIdx.x & 7;          // = ty>>1  (band residue)
    const int i   = blockIdx.x >> 3;         // 0..383
    const int c   = i >> 7;                  // chunk 0..2
    const int rem = i & 127;
    const int bb  = rem >> 5;                // batch 0..3
    const int ty  = 2*v + ((rem >> 4) & 1);
    const int tx  = rem & 15;
    const int bkt = bb*256 + ty*16 + tx;

    const int n   = min(counts[bkt*CSTRIDE], CAP);
    const int np  = min(n - c*64, 64);
    if (np <= 0) return;
    const int t   = threadIdx.x;

    if (t < 128) {
        W2s[t*2]   = W2[t];
        W2s[t*2+1] = W2[ND + t];
        b1s[t]     = b1[t];
    }

    // ---- Phase A: gather. 8 threads/pt, 16 fp8 channels each. ----
    {
        const int pt = t >> 3;
        const int c8 = t & 7;
        if (pt < np) {
            const int g = order[bkt*CAP + c*64 + pt];
            if (c8 == 0) gidx[pt] = g;
            const int b = g >> 14;
            const float cx = coords[(size_t)g*2 + 0];
            const float cy = coords[(size_t)g*2 + 1];
            const float ix = cx * (float)(NW - 1);
            const float iy = cy * (float)(NH - 1);
            const float x0f = floorf(ix), y0f = floorf(iy);
            const int x0 = (int)x0f, y0 = (int)y0f;
            const float wx1 = ix - x0f, wy1 = iy - y0f;
            const float wxv[4] = {1.f - wx1, 1.f, 1.f, wx1};
            const float wyv[4] = {1.f - wy1, 1.f, 1.f, wy1};
            floatx2 acc[8];
            #pragma unroll
            for (int k = 0; k < 8; ++k) acc[k] = (floatx2)(0.f);
            const unsigned char* vmb = vm + (size_t)b*NHW*ND + c8*16;
            #pragma unroll
            for (int j = 0; j < 4; ++j) {
                const int Y  = y0 - 1 + j;
                const int Yc = min(max(Y, 0), NH-1);
                const bool vy = (Y >= 0) & (Y < NH);
                #pragma unroll
                for (int i2 = 0; i2 < 4; ++i2) {
                    const int X  = x0 - 1 + i2;
                    const int Xc = min(max(X, 0), NW-1);
                    const bool vx = (X >= 0) & (X < NW);
                    const float wgt = (vx & vy) ? wxv[i2]*wyv[j] : 0.f;
                    uint4 u = *(const uint4*)(vmb + (size_t)(Yc*NW + Xc)*ND);
                    const floatx2 w2 = {wgt, wgt};
                    acc[0] += w2 * fp8x2_to_f32<false>(u.x);
                    acc[1] += w2 * fp8x2_to_f32<true >(u.x);
                    acc[2] += w2 * fp8x2_to_f32<false>(u.y);
                    acc[3] += w2 * fp8x2_to_f32<true >(u.y);
                    acc[4] += w2 * fp8x2_to_f32<false>(u.z);
                    acc[5] += w2 * fp8x2_to_f32<true >(u.z);
                    acc[6] += w2 * fp8x2_to_f32<false>(u.w);
                    acc[7] += w2 * fp8x2_to_f32<true >(u.w);
                }
            }
            const float s9 = 1.f/9.f;
            unsigned pk[8];
            #pragma unroll
            for (int k = 0; k < 8; ++k)
                pk[k] = pk_bf16(acc[k].x*s9, acc[k].y*s9);
            *(uint4*)&feat[pt*FS + c8*16]     = make_uint4(pk[0],pk[1],pk[2],pk[3]);
            *(uint4*)&feat[pt*FS + c8*16 + 8] = make_uint4(pk[4],pk[5],pk[6],pk[7]);
        }
    }
    __syncthreads();

    // ---- Phase B: MFMA MLP. wave w: e-pair mp=w&3, pt-pair npr=w>>2. ----
    {
        const int lane = t & 63;
        const int w    = t >> 6;
        const int l15  = lane & 15;
        const int q    = lane >> 4;
        const int mp   = w & 3;
        const int npr  = w >> 2;

        if (npr*32 < np) {   // skip waves whose pt-tile is entirely past np
            floatx4 C[2][2];
            #pragma unroll
            for (int mi = 0; mi < 2; ++mi)
                #pragma unroll
                for (int ni = 0; ni < 2; ++ni) C[mi][ni] = (floatx4)(0.f);

            #pragma unroll
            for (int kk = 0; kk < 4; ++kk) {
                short8 a0 = *(const short8*)&W1bf[((mp*2+0)*16 + l15)*ND + kk*32 + q*8];
                short8 a1 = *(const short8*)&W1bf[((mp*2+1)*16 + l15)*ND + kk*32 + q*8];
                short8 f0 = *(const short8*)&feat[((npr*2+0)*16 + l15)*FS + kk*32 + q*8];
                short8 f1 = *(const short8*)&feat[((npr*2+1)*16 + l15)*FS + kk*32 + q*8];
                C[0][0] = __builtin_amdgcn_mfma_f32_16x16x32_bf16(a0, f0, C[0][0], 0, 0, 0);
                C[0][1] = __builtin_amdgcn_mfma_f32_16x16x32_bf16(a0, f1, C[0][1], 0, 0, 0);
                C[1][0] = __builtin_amdgcn_mfma_f32_16x16x32_bf16(a1, f0, C[1][0], 0, 0, 0);
                C[1][1] = __builtin_amdgcn_mfma_f32_16x16x32_bf16(a1, f1, C[1][1], 0, 0, 0);
            }
            // epilogue: e = (mp*2+mi)*16 + q*4 + reg ; pt = (npr*2+ni)*16 + l15
            #pragma unroll
            for (int ni = 0; ni < 2; ++ni) {
                float s0 = 0.f, s1 = 0.f;
                #pragma unroll
                for (int mi = 0; mi < 2; ++mi) {
                    const int e0 = (mp*2 + mi)*16 + q*4;
                    float4 bq = *(const float4*)&b1s[e0];
                    floatx4 h4 = C[mi][ni];
                    #pragma unroll
                    for (int r = 0; r < 4; ++r) {
                        float hv = fmaxf(h4[r] + (&bq.x)[r], 0.f);
                        float2 wv = *(const float2*)&W2s[(e0 + r)*2];
                        s0 = fmaf(hv, wv.x, s0);
                        s1 = fmaf(hv, wv.y, s1);
                    }
                }
                s0 += __shfl_xor(s0, 16); s0 += __shfl_xor(s0, 32);
                s1 += __shfl_xor(s1, 16); s1 += __shfl_xor(s1, 32);
                if (q == 0) {
                    const int pt = (npr*2 + ni)*16 + l15;
                    part[pt][mp*2 + 0] = s0;
                    part[pt][mp*2 + 1] = s1;
                }
            }
        }
    }
    __syncthreads();

    // ---- Phase C: reduce 4 e-pairs, tanh, scatter-write ----
    if (t < np) {
        const int g = gidx[t];
        float s0 = part[t][0] + part[t][2] + part[t][4] + part[t][6];
        float s1 = part[t][1] + part[t][3] + part[t][5] + part[t][7];
        const float cx = coords[(size_t)g*2 + 0];
        const float cy = coords[(size_t)g*2 + 1];
        const float MD = 0.5f / 512.0f;
        float2 o = make_float2(cx + tanhf(s0 + b2[0]) * MD,
                               cy + tanhf(s1 + b2[1]) * MD);
        *(float2*)&out[(size_t)g*2] = o;
    }
}

extern "C" void kernel_launch(void* const* d_in, const int* in_sizes, int n_in,
                              void* d_out, int out_size, void* d_ws, size_t ws_size,
                              hipStream_t stream)
{
    const float* fmap   = (const float*)d_in[0];
    const float* coords = (const float*)d_in[1];
    const float* Wp     = (const float*)d_in[2];
    const float* W1     = (const float*)d_in[3];
    const float* b1     = (const float*)d_in[4];
    const float* W2     = (const float*)d_in[5];
    const float* b2     = (const float*)d_in[6];
    float* out = (float*)d_out;

    // ws layout
    unsigned char* vm = (unsigned char*)d_ws;                         // 8 MB fp8
    char* base = (char*)d_ws + (size_t)NB*NHW*ND;
    unsigned short* W1bf = (unsigned short*)base;                     // 32 KB bf16
    unsigned char* Wpbf8 = (unsigned char*)(base + 32768);            // 32 KB fp8 frags
    int* counts = (int*)(base + 65536);                               // 64 KB (padded)
    int* order  = (int*)(base + 65536 + 65536);                       // 768 KB

    prep_kernel<<<dim3(64),   512, 0, stream>>>(Wp, W1, counts, W1bf, Wpbf8);
    proj_fused <<<dim3(512),  512, 0, stream>>>(fmap, coords, Wpbf8,
                                                counts, order, vm);
    gather_mlp <<<dim3(GGRID),512, 0, stream>>>(vm, coords, counts, order,
                                                W1bf, b1, W2, b2, out);
}